// Round 1
// baseline (108.966 us; speedup 1.0000x reference)
//
#include <hip/hip_runtime.h>
#include <hip/hip_bf16.h>

// Problem constants (match reference)
#define BATCH 4096
#define NC    1024   // n_concepts (K)
#define NL    512    // n_lemmas   (N)
#define TSTEPS 50
#define GAMMA_C 0.95f
#define KAPPA_C 0.1f
#define FLOOR_C 1e-6f

typedef __attribute__((ext_vector_type(8))) short short8;  // 8 bf16 = 4 VGPRs
typedef __attribute__((ext_vector_type(4))) float f32x4;   // MFMA C/D frag

// ---------------- packed split fp32 -> bf16 hi + bf16 lo (RNE both) --------
__device__ __forceinline__ void split2_pk(float x0, float x1,
                                          unsigned& hp, unsigned& lp) {
    union { __hip_bfloat162 b; unsigned u; } ch, cl;
    ch.b = __float22bfloat162_rn(make_float2(x0, x1));
    hp = ch.u;
    const float hf0 = __uint_as_float(hp << 16);
    const float hf1 = __uint_as_float(hp & 0xFFFF0000u);
    cl.b = __float22bfloat162_rn(make_float2(x0 - hf0, x1 - hf1));
    lp = cl.u;
}

// ---- convert BOTH W and A (c_lex) fp32 -> bf16 hi/lo, 8 floats/thread -----
// R13 theory: hoisting the A-split out of the GEMM lets the GEMM stage all
// four operands via global_load_lds (m193: +67% on this structural change),
// at the cost of one ~38 MB streaming pass (~6 us).
#define W_FLOATS (NL * NC)                   // 524288
#define W_BLOCKS (W_FLOATS / (256 * 8))      // 256
#define A_BLOCKS ((BATCH * NC) / (256 * 8))  // 2048

__global__ __launch_bounds__(256)
void convert_hilo(const float* __restrict__ W, const float* __restrict__ A,
                  unsigned short* __restrict__ Whi, unsigned short* __restrict__ Wlo,
                  unsigned short* __restrict__ Ahi, unsigned short* __restrict__ Alo) {
    const int b = blockIdx.x;
    const float* src;
    unsigned short *dh, *dl;
    if (b < W_BLOCKS) {
        const size_t fidx = ((size_t)b * 256 + threadIdx.x) * 8;
        src = W + fidx; dh = Whi + fidx; dl = Wlo + fidx;
    } else {
        const size_t fidx = ((size_t)(b - W_BLOCKS) * 256 + threadIdx.x) * 8;
        src = A + fidx; dh = Ahi + fidx; dl = Alo + fidx;
    }
    const float4 v0 = ((const float4*)src)[0];
    const float4 v1 = ((const float4*)src)[1];
    uint4 h, l;
    split2_pk(v0.x, v0.y, h.x, l.x);
    split2_pk(v0.z, v0.w, h.y, l.y);
    split2_pk(v1.x, v1.y, h.z, l.z);
    split2_pk(v1.z, v1.w, h.w, l.w);
    *(uint4*)dh = h;
    *(uint4*)dl = l;
}

// ------- full-wave (64-lane) sum, broadcast to all lanes, via DPP ----------
__device__ __forceinline__ float wave_sum_bcast(float x) {
    float f = x;
    f += __int_as_float(__builtin_amdgcn_update_dpp(
            0, __float_as_int(f), 0x111, 0xf, 0xf, true));   // row_shr:1
    f += __int_as_float(__builtin_amdgcn_update_dpp(
            0, __float_as_int(f), 0x112, 0xf, 0xf, true));   // row_shr:2
    f += __int_as_float(__builtin_amdgcn_update_dpp(
            0, __float_as_int(f), 0x114, 0xf, 0xf, true));   // row_shr:4
    f += __int_as_float(__builtin_amdgcn_update_dpp(
            0, __float_as_int(f), 0x118, 0xf, 0xf, true));   // row_shr:8
    f += __int_as_float(__builtin_amdgcn_update_dpp(
            0, __float_as_int(f), 0x142, 0xa, 0xf, true));   // row_bcast:15
    f += __int_as_float(__builtin_amdgcn_update_dpp(
            0, __float_as_int(f), 0x143, 0xc, 0xf, true));   // row_bcast:31
    return __int_as_float(__builtin_amdgcn_readlane(__float_as_int(f), 63));
}

// ------------- MFMA GEMM: D = Ahi*Whi^T + Ahi*Wlo^T + Alo*Whi^T -------------
// All-bf16 operands -> pure global_load_lds staging (no staging VALU, no
// reg round trip), double-buffered LDS. Fragment layout / MFMA loop /
// epilogue identical to the previously verified kernel (LDT 40 -> 32;
// [128][32] rows at 64 B stride give an even bank-group distribution for
// ds_read_b128, so the pad is not needed once writes are DMA).
// Block 128x128, 256 thr = 4 waves (2Mx2N), wave-tile 64x64, GK=32,
// splitK=4 (kPerSplit=256, NST=8) -> grid (32,4,4) = 512 blocks, 2/CU.
#define TM 128
#define TN 128
#define GK 32
#define NST 8     // kPerSplit / GK = 256 / 32

// global -> LDS DMA, 16 B per lane; LDS dest is wave-uniform base + lane*16
__device__ __forceinline__ void glds16(const unsigned short* g, unsigned short* l) {
    __builtin_amdgcn_global_load_lds(
        (__attribute__((address_space(1))) void*)(g),
        (__attribute__((address_space(3))) void*)(l), 16, 0, 0);
}

__global__ __launch_bounds__(256)
void gemm_bf16x2(const unsigned short* __restrict__ Ahi, const unsigned short* __restrict__ Alo,
                 const unsigned short* __restrict__ Whi, const unsigned short* __restrict__ Wlo,
                 float* __restrict__ Dp) {
    // 2 buffers x 4 arrays (AsH, AsL, BsH, BsL) x [128][32] bf16 = 64 KB
    __shared__ unsigned short S[2][4][TM * GK];

    const int tid  = threadIdx.x;
    const int lane = tid & 63;
    const int w    = tid >> 6;
    const int m0 = blockIdx.x * TM;
    const int n0 = blockIdx.y * TN;
    const int kb = blockIdx.z * (GK * NST);

    // staging: wave w owns rows [w*32, w*32+32) of each array; 2 calls/array.
    // call c: row = w*32 + c*16 + (lane>>2), col = (lane&3)*8 elements.
    const int srow = w * 32 + (lane >> 2);
    const int scol = (lane & 3) * 8;
    const unsigned short* gAh = Ahi + (size_t)(m0 + srow) * NC + kb + scol;
    const unsigned short* gAl = Alo + (size_t)(m0 + srow) * NC + kb + scol;
    const unsigned short* gBh = Whi + (size_t)(n0 + srow) * NC + kb + scol;
    const unsigned short* gBl = Wlo + (size_t)(n0 + srow) * NC + kb + scol;
    const int ld0 = (w * 32) * GK + lane * 8;   // element offset; +c*16*GK

    const int mw   = (w >> 1) * 64;
    const int nw   = (w & 1) * 64;
    const int sr   = lane & 15;
    const int quad = lane >> 4;
    const int rA = (mw + sr) * GK + quad * 8;
    const int rB = (nw + sr) * GK + quad * 8;

    f32x4 acc[4][4];
    #pragma unroll
    for (int i = 0; i < 4; ++i)
        #pragma unroll
        for (int j = 0; j < 4; ++j)
            acc[i][j] = (f32x4){0.f, 0.f, 0.f, 0.f};

    #define STAGE(buf, kofs)                                          \
        {                                                             \
            const int ko = (kofs);                                    \
            glds16(gAh + ko,           &S[buf][0][ld0]);              \
            glds16(gAh + ko + 16 * NC, &S[buf][0][ld0 + 16 * GK]);    \
            glds16(gAl + ko,           &S[buf][1][ld0]);              \
            glds16(gAl + ko + 16 * NC, &S[buf][1][ld0 + 16 * GK]);    \
            glds16(gBh + ko,           &S[buf][2][ld0]);              \
            glds16(gBh + ko + 16 * NC, &S[buf][2][ld0 + 16 * GK]);    \
            glds16(gBl + ko,           &S[buf][3][ld0]);              \
            glds16(gBl + ko + 16 * NC, &S[buf][3][ld0 + 16 * GK]);    \
        }

    // prologue: stage 0 into buf 0 (syncthreads drains vmcnt before barrier)
    STAGE(0, 0);
    __syncthreads();

    #pragma unroll
    for (int s = 0; s < NST; ++s) {
        const int cur = s & 1;
        if (s + 1 < NST)
            STAGE(cur ^ 1, (s + 1) * GK);   // DMA next stage; lands under MFMA

        short8 afh[4], afl[4], bfh[4], bfl[4];
        #pragma unroll
        for (int mi = 0; mi < 4; ++mi) {
            afh[mi] = *(const short8*)&S[cur][0][rA + mi * 16 * GK];
            afl[mi] = *(const short8*)&S[cur][1][rA + mi * 16 * GK];
        }
        #pragma unroll
        for (int ni = 0; ni < 4; ++ni) {
            bfh[ni] = *(const short8*)&S[cur][2][rB + ni * 16 * GK];
            bfl[ni] = *(const short8*)&S[cur][3][rB + ni * 16 * GK];
        }

        // 48 MFMAs: 16 sites x (hi*hi + hi*lo + lo*hi)
        #pragma unroll
        for (int mi = 0; mi < 4; ++mi) {
            #pragma unroll
            for (int ni = 0; ni < 4; ++ni) {
                acc[mi][ni] = __builtin_amdgcn_mfma_f32_16x16x32_bf16(
                    afh[mi], bfh[ni], acc[mi][ni], 0, 0, 0);
                acc[mi][ni] = __builtin_amdgcn_mfma_f32_16x16x32_bf16(
                    afh[mi], bfl[ni], acc[mi][ni], 0, 0, 0);
                acc[mi][ni] = __builtin_amdgcn_mfma_f32_16x16x32_bf16(
                    afl[mi], bfh[ni], acc[mi][ni], 0, 0, 0);
            }
        }
        __syncthreads();   // drains vmcnt (next-stage DMA) + lgkm for all waves
    }

    // epilogue: C/D layout col = lane&15, row = quad*4 + reg  [m89/m91]
    float* Dz = Dp + (size_t)blockIdx.z * BATCH * NL;
    #pragma unroll
    for (int mi = 0; mi < 4; ++mi) {
        #pragma unroll
        for (int ni = 0; ni < 4; ++ni) {
            const int col = n0 + nw + ni * 16 + sr;
            #pragma unroll
            for (int r = 0; r < 4; ++r) {
                const int row = m0 + mw + mi * 16 + quad * 4 + r;
                Dz[(size_t)row * NL + col] = acc[mi][ni][r];
            }
        }
    }
}

// ------ 50-step recurrence + selection: 64 lanes per row, 8 cols/lane -------
template<int SK>
__global__ __launch_bounds__(256)
void iterate_select(const float* __restrict__ Dp,
                    float* __restrict__ a_out,
                    float* __restrict__ sel_out, float* __restrict__ conf_out) {
    const int lane = threadIdx.x & 63;
    const int wave = threadIdx.x >> 6;
    const int row  = blockIdx.x * 4 + wave;

    float d[8];
    {
        float4 v[SK][2];
        #pragma unroll
        for (int s = 0; s < SK; ++s) {
            const float4* ps = (const float4*)(Dp + (size_t)s * BATCH * NL
                                               + (size_t)row * NL + lane * 8);
            v[s][0] = ps[0];
            v[s][1] = ps[1];
        }
        d[0] = v[0][0].x; d[1] = v[0][0].y; d[2] = v[0][0].z; d[3] = v[0][0].w;
        d[4] = v[0][1].x; d[5] = v[0][1].y; d[6] = v[0][1].z; d[7] = v[0][1].w;
        #pragma unroll
        for (int s = 1; s < SK; ++s) {
            d[0] += v[s][0].x; d[1] += v[s][0].y; d[2] += v[s][0].z; d[3] += v[s][0].w;
            d[4] += v[s][1].x; d[5] += v[s][1].y; d[6] += v[s][1].z; d[7] += v[s][1].w;
        }
    }

    float a[8];
    #pragma unroll
    for (int j = 0; j < 8; ++j) a[j] = 0.f;

    const float K1 = 1.0f + KAPPA_C;

    for (int t = 0; t < TSTEPS; ++t) {
        #pragma unroll
        for (int j = 0; j < 8; ++j) a[j] = fmaf(GAMMA_C, a[j], d[j]);

        float t4a = a[0] + a[4], t4b = a[1] + a[5], t4c = a[2] + a[6], t4d = a[3] + a[7];
        float t2a = t4a + t4c, t2b = t4b + t4d;
        const float S = wave_sum_bcast(t2a + t2b);

        const float h = -KAPPA_C * S;
        #pragma unroll
        for (int j = 0; j < 8; ++j) {
            const float v = fmaf(K1, a[j], h);
            a[j] = v > 0.f ? v : 0.f;
        }
    }

    // ---- epilogue (runs once): peak, sum, confidence, first-index argmax ----
    float m4a = fmaxf(a[0], a[4]), m4b = fmaxf(a[1], a[5]);
    float m4c = fmaxf(a[2], a[6]), m4d = fmaxf(a[3], a[7]);
    float peak = fmaxf(fmaxf(m4a, m4b), fmaxf(m4c, m4d));
    float s4a = a[0] + a[4], s4b = a[1] + a[5], s4c = a[2] + a[6], s4d = a[3] + a[7];
    float ssum = wave_sum_bcast((s4a + s4b) + (s4c + s4d));

    #pragma unroll
    for (int m = 1; m < 64; m <<= 1)
        peak = fmaxf(peak, __shfl_xor(peak, m, 64));

    const float mean = ssum * (1.0f / (float)NL);
    const float conf = peak / fmaxf(mean, FLOOR_C);

    int idx = 0x7fffffff;
    #pragma unroll
    for (int j = 0; j < 8; ++j)
        if (a[j] == peak) idx = min(idx, lane * 8 + j);
    #pragma unroll
    for (int m = 1; m < 64; m <<= 1)
        idx = min(idx, __shfl_xor(idx, m, 64));

    float4* ar = (float4*)(a_out + (size_t)row * NL + lane * 8);
    float4 o0, o1;
    o0.x = a[0]; o0.y = a[1]; o0.z = a[2]; o0.w = a[3];
    o1.x = a[4]; o1.y = a[5]; o1.z = a[6]; o1.w = a[7];
    ar[0] = o0; ar[1] = o1;

    if (lane == 0) {
        if (sel_out)  sel_out[row]  = (float)idx;
        if (conf_out) conf_out[row] = conf;
    }
}

extern "C" void kernel_launch(void* const* d_in, const int* in_sizes, int n_in,
                              void* d_out, int out_size, void* d_ws, size_t ws_size,
                              hipStream_t stream) {
    const float* c_lex = (const float*)d_in[0];
    const float* W     = (const float*)d_in[1];
    // d_in[2] = a0 (zeros at every reset; recurrence inits a=0 directly)

    // workspace layout: 4 D-partials (33.6 MB) + Whi/Wlo (2.1 MB) + Ahi/Alo (16.8 MB)
    float* D = (float*)d_ws;
    unsigned short* Whi = (unsigned short*)(D + 4ull * BATCH * NL);
    unsigned short* Wlo = Whi + (size_t)NL * NC;
    unsigned short* Ahi = Wlo + (size_t)NL * NC;
    unsigned short* Alo = Ahi + (size_t)BATCH * NC;

    float* a_out = (float*)d_out;
    float* sel   = nullptr;
    float* conf  = nullptr;
    const int base = BATCH * NL;
    if (out_size >= base + 2 * BATCH) {        // (a, selected, confidence)
        sel  = a_out + base;
        conf = a_out + base + BATCH;
    } else if (out_size >= base + BATCH) {     // (a, confidence)
        conf = a_out + base;
    }

    // 1) W and A fp32 -> bf16 hi/lo (one streaming pass)
    convert_hilo<<<dim3(W_BLOCKS + A_BLOCKS), 256, 0, stream>>>(
        W, c_lex, Whi, Wlo, Ahi, Alo);

    // 2) MFMA GEMM, all-bf16 operands, global_load_lds double-buffered, splitK=4
    gemm_bf16x2<<<dim3(BATCH / TM, NL / TN, 4), 256, 0, stream>>>(
        Ahi, Alo, Whi, Wlo, D);

    // 3) recurrence + selection: 1 row/wave, 4 waves/SIMD, DPP row-sum
    iterate_select<4><<<dim3(BATCH / 4), 256, 0, stream>>>(D, a_out, sel, conf);
}